// Round 3
// baseline (309.378 us; speedup 1.0000x reference)
//
#include <hip/hip_runtime.h>

typedef __bf16 bf16x8 __attribute__((ext_vector_type(8)));
typedef float  f32x4  __attribute__((ext_vector_type(4)));

__device__ __forceinline__ ushort f2b(float f){
  union { float f; uint i; } v; v.f = f; uint u = v.i;
  return (ushort)((u + 0x7FFFu + ((u >> 16) & 1u)) >> 16);
}
__device__ __forceinline__ uint pack2(float a, float b){
  return (uint)f2b(a) | ((uint)f2b(b) << 16);
}
__device__ __forceinline__ bf16x8 ldfrag(const ushort* p){
  return *reinterpret_cast<const bf16x8*>(p);
}
__device__ __forceinline__ f32x4 relu4(f32x4 x){
  f32x4 r;
  r[0]=fmaxf(x[0],0.f); r[1]=fmaxf(x[1],0.f);
  r[2]=fmaxf(x[2],0.f); r[3]=fmaxf(x[3],0.f);
  return r;
}

// Pre-kernel: fp32 weights -> transposed bf16 layouts in workspace.
// W1ftr[n][k] (96x128) = bf16(fc1_W[3+k][n]);  W2tr[n][k] (64x96) = bf16(fc2_W[k][n]).
__global__ void omd_transpose(const float* __restrict__ fc1W, const float* __restrict__ fc2W,
                              ushort* __restrict__ W1ftr, ushort* __restrict__ W2tr){
  int t = blockIdx.x * 256 + threadIdx.x;
  if (t < 96*128){
    int n = t >> 7, k = t & 127;
    W1ftr[t] = f2b(fc1W[(3 + k)*96 + n]);
  } else {
    int e = t - 96*128;
    if (e < 64*96){
      int n = e / 96, k = e - n*96;
      W2tr[e] = f2b(fc2W[k*64 + n]);
    }
  }
}

__global__ __launch_bounds__(256, 2) void omd_main(
    const float* __restrict__ points, const float* __restrict__ feats,
    const int*   __restrict__ batch,  const float* __restrict__ decW,
    const float* __restrict__ decb,   const float* __restrict__ fc1W,
    const float* __restrict__ fc1b,   const float* __restrict__ fc2b,
    const ushort* __restrict__ W1ftr, const ushort* __restrict__ W2tr,
    float* __restrict__ out, int npts)
{
  __shared__ __align__(16) float  pfL[32*32];      // point_features tile (fp32)
  __shared__ float decWL[32*24];
  __shared__ float decbL[24];
  __shared__ float w1pL[3*96];                     // fc1_W rows 0..2 (fp32)
  __shared__ float relL[32*24];                    // rel, fp32
  __shared__ __align__(16) ushort ffL[32*136];     // feature_features bf16, stride 136
  __shared__ __align__(16) float  s1L[32*100];     // s1 = ff@W1f+b1, pad 96->100
  __shared__ __align__(16) ushort hL[2*32*104];    // h for a neighbor pair, stride 104

  const int t    = threadIdx.x;
  const int w    = t >> 6;
  const int lane = t & 63;
  const int q    = lane >> 4;
  const int c    = lane & 15;
  const int pbase = blockIdx.x * 32;

  const size_t offF = (size_t)npts * 24;                    // fc2 output offset
  const size_t offB = (size_t)npts * 24 + (size_t)npts * 512; // batch output offset

  // ---- stage LDS ----
  {
    // point features: 32 rows x 32 floats
    int p = t >> 3, v = t & 7;
    const f32x4* src = (const f32x4*)(feats + (size_t)(pbase + p)*160);
    ((f32x4*)pfL)[p*8 + v] = src[v];
  }
  {
    // feature features: 32 rows x 128 floats -> bf16 LDS (stride 136)
    int m = t >> 3, seg = t & 7;
    const f32x4* src = (const f32x4*)(feats + (size_t)(pbase + m)*160 + 32 + seg*16);
    uint* dst = (uint*)(ffL + m*136 + seg*16);
    #pragma unroll
    for (int r = 0; r < 4; ++r){
      f32x4 f = src[r];
      dst[r*2    ] = pack2(f[0], f[1]);
      dst[r*2 + 1] = pack2(f[2], f[3]);
    }
  }
  for (int e = t; e < 768; e += 256) decWL[e] = decW[e];
  if (t < 24) decbL[t] = decb[t];
  for (int e = t; e < 288; e += 256) w1pL[e] = fc1W[e];

  // ---- W2 B-fragments resident in registers ----
  bf16x8 w2f[4][3];
  #pragma unroll
  for (int nt = 0; nt < 4; ++nt)
    #pragma unroll
    for (int kt = 0; kt < 3; ++kt)
      w2f[nt][kt] = ldfrag(W2tr + (nt*16 + c)*96 + kt*32 + q*8);

  __syncthreads();

  // ---- phase 1: rel = pf @ dec_W + dec_b  (VALU, 768 outputs) ----
  #pragma unroll
  for (int oo = 0; oo < 3; ++oo){
    int o = t + 256*oo;
    int p = o / 24, col = o - p*24;
    float a = decbL[col];
    #pragma unroll
    for (int k = 0; k < 32; ++k)
      a += pfL[p*32 + k] * decWL[k*24 + col];
    relL[o] = a;
  }

  // ---- phase 2: s1 = ff @ W1f + b1  (MFMA 16x16x32, A from LDS) ----
  {
    int mt = w & 1, trio = w >> 1;
    const ushort* arow = ffL + (mt*16 + c)*136 + q*8;
    bf16x8 a0 = ldfrag(arow);
    bf16x8 a1 = ldfrag(arow + 32);
    bf16x8 a2 = ldfrag(arow + 64);
    bf16x8 a3 = ldfrag(arow + 96);
    #pragma unroll
    for (int i = 0; i < 3; ++i){
      const ushort* brow = W1ftr + ((trio*3 + i)*16 + c)*128 + q*8;
      f32x4 acc = {0.f, 0.f, 0.f, 0.f};
      acc = __builtin_amdgcn_mfma_f32_16x16x32_bf16(a0, ldfrag(brow      ), acc, 0, 0, 0);
      acc = __builtin_amdgcn_mfma_f32_16x16x32_bf16(a1, ldfrag(brow + 32 ), acc, 0, 0, 0);
      acc = __builtin_amdgcn_mfma_f32_16x16x32_bf16(a2, ldfrag(brow + 64 ), acc, 0, 0, 0);
      acc = __builtin_amdgcn_mfma_f32_16x16x32_bf16(a3, ldfrag(brow + 96 ), acc, 0, 0, 0);
      int col = (trio*3 + i)*16 + c;
      float bb = fc1b[col];
      #pragma unroll
      for (int r = 0; r < 4; ++r)
        s1L[(mt*16 + q*4 + r)*100 + col] = acc[r] + bb;
    }
  }
  __syncthreads();

  // ---- neighbor pairs: h = relu(s1 + rel@W1p3) -> fc2 = relu(h@W2+b2) ----
  #pragma unroll 1
  for (int pair = 0; pair < 4; ++pair){
    {
      int m  = t >> 3;
      int jb = (t & 7) * 12;
      const f32x4* s1v = (const f32x4*)&s1L[m*100 + jb];
      f32x4 s0 = s1v[0], s1_ = s1v[1], s2 = s1v[2];
      f32x4 wa0 = *(const f32x4*)&w1pL[jb],     wa1 = *(const f32x4*)&w1pL[jb+4],     wa2 = *(const f32x4*)&w1pL[jb+8];
      f32x4 wb0 = *(const f32x4*)&w1pL[96+jb],  wb1 = *(const f32x4*)&w1pL[96+jb+4],  wb2 = *(const f32x4*)&w1pL[96+jb+8];
      f32x4 wc0 = *(const f32x4*)&w1pL[192+jb], wc1 = *(const f32x4*)&w1pL[192+jb+4], wc2 = *(const f32x4*)&w1pL[192+jb+8];
      uint* hLu = (uint*)hL;
      #pragma unroll
      for (int nl = 0; nl < 2; ++nl){
        int n = pair*2 + nl;
        float r0 = relL[m*24 + 3*n], r1 = relL[m*24 + 3*n + 1], r2 = relL[m*24 + 3*n + 2];
        f32x4 h0 = relu4(s0  + r0*wa0 + r1*wb0 + r2*wc0);
        f32x4 h1 = relu4(s1_ + r0*wa1 + r1*wb1 + r2*wc1);
        f32x4 h2 = relu4(s2  + r0*wa2 + r1*wb2 + r2*wc2);
        int ub = nl*1664 + m*52 + (t & 7)*6;   // uint index into hL (stride 104 bf16 = 52 uints)
        hLu[ub    ] = pack2(h0[0], h0[1]);
        hLu[ub + 1] = pack2(h0[2], h0[3]);
        hLu[ub + 2] = pack2(h1[0], h1[1]);
        hLu[ub + 3] = pack2(h1[2], h1[3]);
        hLu[ub + 4] = pack2(h2[0], h2[1]);
        hLu[ub + 5] = pack2(h2[2], h2[3]);
      }
    }
    __syncthreads();

    {
      int nl = w & 1, mtw = w >> 1;
      const ushort* hrow = hL + nl*3328 + (mtw*16 + c)*104 + q*8;
      bf16x8 ha0 = ldfrag(hrow);
      bf16x8 ha1 = ldfrag(hrow + 32);
      bf16x8 ha2 = ldfrag(hrow + 64);
      int n = pair*2 + nl;
      int prow0 = pbase + mtw*16 + q*4;
      #pragma unroll
      for (int nt = 0; nt < 4; ++nt){
        float bb = fc2b[nt*16 + c];
        f32x4 acc = {bb, bb, bb, bb};
        acc = __builtin_amdgcn_mfma_f32_16x16x32_bf16(ha0, w2f[nt][0], acc, 0, 0, 0);
        acc = __builtin_amdgcn_mfma_f32_16x16x32_bf16(ha1, w2f[nt][1], acc, 0, 0, 0);
        acc = __builtin_amdgcn_mfma_f32_16x16x32_bf16(ha2, w2f[nt][2], acc, 0, 0, 0);
        #pragma unroll
        for (int r = 0; r < 4; ++r){
          size_t g = (size_t)(prow0 + r)*8 + n;
          out[offF + g*64 + nt*16 + c] = fmaxf(acc[r], 0.f);
        }
      }
    }
    __syncthreads();
  }

  // ---- phase 4: output_points and output_batch ----
  #pragma unroll
  for (int i = 0; i < 3; ++i){
    int e = t + 256*i;
    int p = e / 24, rem = e - p*24;
    int d = rem % 3;
    float v = points[(size_t)(pbase + p)*3 + d] + 0.5f * relL[e];
    out[(size_t)(pbase + p)*24 + rem] = v;
  }
  {
    int p = t >> 3, n = t & 7;
    out[offB + (size_t)(pbase + p)*8 + n] = (float)batch[pbase + p];
  }
}

extern "C" void kernel_launch(void* const* d_in, const int* in_sizes, int n_in,
                              void* d_out, int out_size, void* d_ws, size_t ws_size,
                              hipStream_t stream){
  const float* points = (const float*)d_in[0];
  const float* feats  = (const float*)d_in[1];
  const int*   batch  = (const int*)d_in[2];
  const float* decW   = (const float*)d_in[3];
  const float* decb   = (const float*)d_in[4];
  const float* fc1W   = (const float*)d_in[5];
  const float* fc1b   = (const float*)d_in[6];
  const float* fc2W   = (const float*)d_in[7];
  const float* fc2b   = (const float*)d_in[8];
  float*  outp  = (float*)d_out;
  ushort* W1ftr = (ushort*)d_ws;
  ushort* W2tr  = W1ftr + 96*128;

  int npts = in_sizes[2];           // 100000, divisible by 32

  omd_transpose<<<72, 256, 0, stream>>>(fc1W, fc2W, W1ftr, W2tr);
  omd_main<<<npts/32, 256, 0, stream>>>(points, feats, batch, decW, decb,
                                        fc1W, fc1b, fc2b, W1ftr, W2tr,
                                        outp, npts);
}

// Round 4
// 307.157 us; speedup vs baseline: 1.0072x; 1.0072x over previous
//
#include <hip/hip_runtime.h>
#include <hip/hip_bf16.h>

typedef __bf16 bf16x8 __attribute__((ext_vector_type(8)));
typedef float  f32x4  __attribute__((ext_vector_type(4)));

__device__ __forceinline__ ushort f2b(float f){
  union { float f; uint i; } v; v.f = f; uint u = v.i;
  return (ushort)((u + 0x7FFFu + ((u >> 16) & 1u)) >> 16);
}
__device__ __forceinline__ uint pack2(float a, float b){
  __hip_bfloat162 h = __float22bfloat162_rn(make_float2(a, b));
  union { __hip_bfloat162 h; uint u; } v; v.h = h; return v.u;
}
__device__ __forceinline__ bf16x8 ldfrag(const ushort* p){
  return *reinterpret_cast<const bf16x8*>(p);
}
__device__ __forceinline__ f32x4 relu4(f32x4 x){
  f32x4 r;
  r[0]=fmaxf(x[0],0.f); r[1]=fmaxf(x[1],0.f);
  r[2]=fmaxf(x[2],0.f); r[3]=fmaxf(x[3],0.f);
  return r;
}

// Pre-kernel: fp32 weights -> transposed bf16 layouts in workspace.
// W1ftr[n][k] (96x128) = bf16(fc1_W[3+k][n]);  W2tr[n][k] (64x96) = bf16(fc2_W[k][n]);
// decWtr[n][k] (32x32, zero-padded n>=24) = bf16(dec_W[k][n]).
__global__ void omd_transpose(const float* __restrict__ fc1W, const float* __restrict__ fc2W,
                              const float* __restrict__ decW,
                              ushort* __restrict__ W1ftr, ushort* __restrict__ W2tr,
                              ushort* __restrict__ decWtr){
  int t = blockIdx.x * 256 + threadIdx.x;
  if (t < 96*128){
    int n = t >> 7, k = t & 127;
    W1ftr[t] = f2b(fc1W[(3 + k)*96 + n]);
  } else if (t < 96*128 + 64*96){
    int e = t - 96*128;
    int n = e / 96, k = e - n*96;
    W2tr[e] = f2b(fc2W[k*64 + n]);
  } else if (t < 96*128 + 64*96 + 32*32){
    int e = t - (96*128 + 64*96);
    int n = e >> 5, k = e & 31;
    decWtr[e] = (n < 24) ? f2b(decW[k*24 + n]) : (ushort)0;
  }
}

__global__ __launch_bounds__(256, 3) void omd_main(
    const float* __restrict__ points, const float* __restrict__ feats,
    const int*   __restrict__ batch,  const float* __restrict__ decb,
    const float* __restrict__ fc1W,   const float* __restrict__ fc1b,
    const float* __restrict__ fc2b,   const ushort* __restrict__ W1ftr,
    const ushort* __restrict__ W2tr,  const ushort* __restrict__ decWtr,
    float* __restrict__ out, int npts)
{
  __shared__ __align__(16) ushort pfB[32*40];      // point_features bf16, stride 40
  __shared__ float decbL[24];
  __shared__ float w1pL[3*96];                     // fc1_W rows 0..2 (fp32)
  __shared__ float relL[32*24];                    // rel, fp32
  __shared__ __align__(16) ushort ffL[32*136];     // feature_features bf16, stride 136
  __shared__ __align__(16) float  s1L[32*100];     // s1 = ff@W1f+b1, pad 96->100
  __shared__ __align__(16) ushort hL[2*32*104];    // h for a neighbor pair, stride 104

  const int t    = threadIdx.x;
  const int w    = t >> 6;
  const int lane = t & 63;
  const int q    = lane >> 4;
  const int c    = lane & 15;
  const int pbase = blockIdx.x * 32;

  const size_t offF = (size_t)npts * 24;                      // fc2 output offset
  const size_t offB = (size_t)npts * 24 + (size_t)npts * 512; // batch output offset

  // ---- stage LDS ----
  {
    // point features: 32 rows x 32 floats -> bf16 (stride 40)
    int p = t >> 3, seg = t & 7;
    const f32x4* src = (const f32x4*)(feats + (size_t)(pbase + p)*160);
    f32x4 f = src[seg];
    uint* dst = (uint*)pfB;
    dst[p*20 + seg*2    ] = pack2(f[0], f[1]);
    dst[p*20 + seg*2 + 1] = pack2(f[2], f[3]);
  }
  {
    // feature features: 32 rows x 128 floats -> bf16 LDS (stride 136)
    int m = t >> 3, seg = t & 7;
    const f32x4* src = (const f32x4*)(feats + (size_t)(pbase + m)*160 + 32 + seg*16);
    uint* dst = (uint*)(ffL + m*136 + seg*16);
    #pragma unroll
    for (int r = 0; r < 4; ++r){
      f32x4 f = src[r];
      dst[r*2    ] = pack2(f[0], f[1]);
      dst[r*2 + 1] = pack2(f[2], f[3]);
    }
  }
  if (t < 24) decbL[t] = decb[t];
  for (int e = t; e < 288; e += 256) w1pL[e] = fc1W[e];

  // ---- W2 B-fragments resident in registers ----
  bf16x8 w2f[4][3];
  #pragma unroll
  for (int nt = 0; nt < 4; ++nt)
    #pragma unroll
    for (int kt = 0; kt < 3; ++kt)
      w2f[nt][kt] = ldfrag(W2tr + (nt*16 + c)*96 + kt*32 + q*8);

  __syncthreads();

  // ---- phase 1: rel = pf @ dec_W + dec_b  (one MFMA per wave) ----
  {
    int mt = w & 1, ntile = w >> 1;           // ntile=1 covers cols 16..23 (c<8)
    bf16x8 a = ldfrag(pfB + (mt*16 + c)*40 + q*8);
    bf16x8 b = ldfrag(decWtr + ((ntile*16 + c)<<5) + q*8);
    f32x4 acc = {0.f, 0.f, 0.f, 0.f};
    acc = __builtin_amdgcn_mfma_f32_16x16x32_bf16(a, b, acc, 0, 0, 0);
    int n = ntile*16 + c;
    if (n < 24){
      float bb = decbL[n];
      #pragma unroll
      for (int r = 0; r < 4; ++r)
        relL[(mt*16 + q*4 + r)*24 + n] = acc[r] + bb;
    }
  }

  // ---- phase 2: s1 = ff @ W1f + b1  (MFMA 16x16x32, A from LDS) ----
  {
    int mt = w & 1, trio = w >> 1;
    const ushort* arow = ffL + (mt*16 + c)*136 + q*8;
    bf16x8 a0 = ldfrag(arow);
    bf16x8 a1 = ldfrag(arow + 32);
    bf16x8 a2 = ldfrag(arow + 64);
    bf16x8 a3 = ldfrag(arow + 96);
    #pragma unroll
    for (int i = 0; i < 3; ++i){
      const ushort* brow = W1ftr + ((trio*3 + i)*16 + c)*128 + q*8;
      f32x4 acc = {0.f, 0.f, 0.f, 0.f};
      acc = __builtin_amdgcn_mfma_f32_16x16x32_bf16(a0, ldfrag(brow      ), acc, 0, 0, 0);
      acc = __builtin_amdgcn_mfma_f32_16x16x32_bf16(a1, ldfrag(brow + 32 ), acc, 0, 0, 0);
      acc = __builtin_amdgcn_mfma_f32_16x16x32_bf16(a2, ldfrag(brow + 64 ), acc, 0, 0, 0);
      acc = __builtin_amdgcn_mfma_f32_16x16x32_bf16(a3, ldfrag(brow + 96 ), acc, 0, 0, 0);
      int col = (trio*3 + i)*16 + c;
      float bb = fc1b[col];
      #pragma unroll
      for (int r = 0; r < 4; ++r)
        s1L[(mt*16 + q*4 + r)*100 + col] = acc[r] + bb;
    }
  }
  __syncthreads();

  // ---- hoist pair-invariant values into registers ----
  const int m  = t >> 3;
  const int jb = (t & 7) * 12;
  f32x4 s0, s1_, s2, wa0, wa1, wa2, wb0, wb1, wb2, wc0, wc1, wc2;
  {
    const f32x4* s1v = (const f32x4*)&s1L[m*100 + jb];
    s0 = s1v[0]; s1_ = s1v[1]; s2 = s1v[2];
    wa0 = *(const f32x4*)&w1pL[jb];     wa1 = *(const f32x4*)&w1pL[jb+4];     wa2 = *(const f32x4*)&w1pL[jb+8];
    wb0 = *(const f32x4*)&w1pL[96+jb];  wb1 = *(const f32x4*)&w1pL[96+jb+4];  wb2 = *(const f32x4*)&w1pL[96+jb+8];
    wc0 = *(const f32x4*)&w1pL[192+jb]; wc1 = *(const f32x4*)&w1pL[192+jb+4]; wc2 = *(const f32x4*)&w1pL[192+jb+8];
  }

  // ---- neighbor pairs: h = relu(s1 + rel@W1p3) -> fc2 = relu(h@W2+b2) ----
  #pragma unroll 1
  for (int pair = 0; pair < 4; ++pair){
    {
      uint* hLu = (uint*)hL;
      #pragma unroll
      for (int nl = 0; nl < 2; ++nl){
        int n = pair*2 + nl;
        float r0 = relL[m*24 + 3*n], r1 = relL[m*24 + 3*n + 1], r2 = relL[m*24 + 3*n + 2];
        f32x4 h0 = relu4(s0  + r0*wa0 + r1*wb0 + r2*wc0);
        f32x4 h1 = relu4(s1_ + r0*wa1 + r1*wb1 + r2*wc1);
        f32x4 h2 = relu4(s2  + r0*wa2 + r1*wb2 + r2*wc2);
        int ub = nl*1664 + m*52 + (t & 7)*6;   // uint index into hL (stride 104 bf16 = 52 uints)
        hLu[ub    ] = pack2(h0[0], h0[1]);
        hLu[ub + 1] = pack2(h0[2], h0[3]);
        hLu[ub + 2] = pack2(h1[0], h1[1]);
        hLu[ub + 3] = pack2(h1[2], h1[3]);
        hLu[ub + 4] = pack2(h2[0], h2[1]);
        hLu[ub + 5] = pack2(h2[2], h2[3]);
      }
    }
    __syncthreads();

    {
      int nl = w & 1, mtw = w >> 1;
      const ushort* hrow = hL + nl*3328 + (mtw*16 + c)*104 + q*8;
      bf16x8 ha0 = ldfrag(hrow);
      bf16x8 ha1 = ldfrag(hrow + 32);
      bf16x8 ha2 = ldfrag(hrow + 64);
      int n = pair*2 + nl;
      int prow0 = pbase + mtw*16 + q*4;
      #pragma unroll
      for (int nt = 0; nt < 4; ++nt){
        float bb = fc2b[nt*16 + c];
        f32x4 acc = {bb, bb, bb, bb};
        acc = __builtin_amdgcn_mfma_f32_16x16x32_bf16(ha0, w2f[nt][0], acc, 0, 0, 0);
        acc = __builtin_amdgcn_mfma_f32_16x16x32_bf16(ha1, w2f[nt][1], acc, 0, 0, 0);
        acc = __builtin_amdgcn_mfma_f32_16x16x32_bf16(ha2, w2f[nt][2], acc, 0, 0, 0);
        #pragma unroll
        for (int r = 0; r < 4; ++r){
          size_t g = (size_t)(prow0 + r)*8 + n;
          out[offF + g*64 + nt*16 + c] = fmaxf(acc[r], 0.f);
        }
      }
    }
    __syncthreads();
  }

  // ---- phase 4: output_points and output_batch ----
  #pragma unroll
  for (int i = 0; i < 3; ++i){
    int e = t + 256*i;
    int p = e / 24, rem = e - p*24;
    int d = rem % 3;
    float v = points[(size_t)(pbase + p)*3 + d] + 0.5f * relL[e];
    out[(size_t)(pbase + p)*24 + rem] = v;
  }
  {
    int p = t >> 3, n = t & 7;
    out[offB + (size_t)(pbase + p)*8 + n] = (float)batch[pbase + p];
  }
}

extern "C" void kernel_launch(void* const* d_in, const int* in_sizes, int n_in,
                              void* d_out, int out_size, void* d_ws, size_t ws_size,
                              hipStream_t stream){
  const float* points = (const float*)d_in[0];
  const float* feats  = (const float*)d_in[1];
  const int*   batch  = (const int*)d_in[2];
  const float* decW   = (const float*)d_in[3];
  const float* decb   = (const float*)d_in[4];
  const float* fc1W   = (const float*)d_in[5];
  const float* fc1b   = (const float*)d_in[6];
  const float* fc2W   = (const float*)d_in[7];
  const float* fc2b   = (const float*)d_in[8];
  float*  outp   = (float*)d_out;
  ushort* W1ftr  = (ushort*)d_ws;
  ushort* W2tr   = W1ftr + 96*128;
  ushort* decWtr = W2tr + 64*96;

  int npts = in_sizes[2];           // 100000, divisible by 32

  omd_transpose<<<76, 256, 0, stream>>>(fc1W, fc2W, decW, W1ftr, W2tr, decWtr);
  omd_main<<<npts/32, 256, 0, stream>>>(points, feats, batch, decb,
                                        fc1W, fc1b, fc2b, W1ftr, W2tr, decWtr,
                                        outp, npts);
}